// Round 3
// baseline (1481.100 us; speedup 1.0000x reference)
//
#include <hip/hip_runtime.h>
#include <cstdint>
#include <cstddef>

#define N_TOK 65536
#define DIM 512
#define FF 2048
#define NE 8

typedef __attribute__((ext_vector_type(8))) short short8;
typedef __attribute__((ext_vector_type(4))) float f32x4;
typedef __attribute__((ext_vector_type(16))) float f32x16;

__device__ __forceinline__ unsigned short f2bf(float f) {
  unsigned u = __builtin_bit_cast(unsigned, f);
  u = u + 0x7fffu + ((u >> 16) & 1u);
  return (unsigned short)(u >> 16);
}

__device__ __forceinline__ void gload_lds16(const void* g, void* l) {
  __builtin_amdgcn_global_load_lds((const __attribute__((address_space(1))) void*)g,
                                   (__attribute__((address_space(3))) void*)l, 16, 0, 0);
}

#define SBAR __builtin_amdgcn_sched_barrier(0)
#define BARN(N) do { SBAR; \
  asm volatile("s_waitcnt vmcnt(" #N ")" ::: "memory"); \
  __builtin_amdgcn_s_barrier(); SBAR; } while (0)
#define BARNL(N) do { SBAR; \
  asm volatile("s_waitcnt vmcnt(" #N ") lgkmcnt(0)" ::: "memory"); \
  __builtin_amdgcn_s_barrier(); SBAR; } while (0)

// ---------------- transpose + cast: in (rows x cols) f32 -> out (cols x rows) bf16, per expert
__global__ __launch_bounds__(256) void k_transpose_cast(
    const float* __restrict__ in, unsigned short* __restrict__ outp, int rows, int cols)
{
  __shared__ float tile[32][33];
  const float* ine = in + (size_t)blockIdx.z * rows * cols;
  unsigned short* oute = outp + (size_t)blockIdx.z * rows * cols;
  int tx = threadIdx.x & 31, ty = threadIdx.x >> 5;
  int r0 = blockIdx.y * 32, c0 = blockIdx.x * 32;
#pragma unroll
  for (int i = 0; i < 4; ++i)
    tile[ty + i*8][tx] = ine[(size_t)(r0 + ty + i*8)*cols + c0 + tx];
  __syncthreads();
#pragma unroll
  for (int i = 0; i < 4; ++i) {
    int r = c0 + ty + i*8, c = r0 + tx;
    oute[(size_t)r*rows + c] = f2bf(tile[tx][ty + i*8]);
  }
}

// ---------------- router: wave per token; block-aggregated expert lists
__global__ __launch_bounds__(256) void k_router(
    const float* __restrict__ x, const float* __restrict__ Wr,
    unsigned short* __restrict__ xb, int* __restrict__ tokl,
    float* __restrict__ pwl, int* __restrict__ cnt)
{
  __shared__ int lcnt[8];
  __shared__ int lbase[8];
  __shared__ int ltk[128];
  __shared__ int lslot[128];
  __shared__ float lwt[128];
  __shared__ unsigned char lex[128];

  int tid = threadIdx.x, lane = tid & 63, wv = tid >> 6;
  if (tid < 8) lcnt[tid] = 0;
  float wr[8][8];
#pragma unroll
  for (int j = 0; j < 8; ++j) {
    const float4* p = (const float4*)(Wr + (size_t)(lane*8 + j)*NE);
    float4 a = p[0], b = p[1];
    wr[j][0]=a.x; wr[j][1]=a.y; wr[j][2]=a.z; wr[j][3]=a.w;
    wr[j][4]=b.x; wr[j][5]=b.y; wr[j][6]=b.z; wr[j][7]=b.w;
  }
  __syncthreads();
  int t0 = blockIdx.x*64 + wv*16;
  for (int it = 0; it < 16; ++it) {
    int t = t0 + it;
    const float4* xp = (const float4*)(x + (size_t)t*DIM + lane*8);
    float4 v0 = xp[0], v1 = xp[1];
    float xv[8] = {v0.x,v0.y,v0.z,v0.w,v1.x,v1.y,v1.z,v1.w};
    uint4 pk;
    pk.x = (unsigned)f2bf(xv[0]) | ((unsigned)f2bf(xv[1]) << 16);
    pk.y = (unsigned)f2bf(xv[2]) | ((unsigned)f2bf(xv[3]) << 16);
    pk.z = (unsigned)f2bf(xv[4]) | ((unsigned)f2bf(xv[5]) << 16);
    pk.w = (unsigned)f2bf(xv[6]) | ((unsigned)f2bf(xv[7]) << 16);
    *(uint4*)(xb + (size_t)t*DIM + lane*8) = pk;
    float lg[8];
#pragma unroll
    for (int e2 = 0; e2 < 8; ++e2) lg[e2] = 0.f;
#pragma unroll
    for (int j = 0; j < 8; ++j)
#pragma unroll
      for (int e2 = 0; e2 < 8; ++e2) lg[e2] += xv[j]*wr[j][e2];
#pragma unroll
    for (int off = 32; off >= 1; off >>= 1)
#pragma unroll
      for (int e2 = 0; e2 < 8; ++e2) lg[e2] += __shfl_xor(lg[e2], off, 64);
    int e0 = 0; float v0m = lg[0];
#pragma unroll
    for (int e2 = 1; e2 < 8; ++e2) if (lg[e2] > v0m) { v0m = lg[e2]; e0 = e2; }
    int e1 = -1; float v1m = -3.0e38f;
#pragma unroll
    for (int e2 = 0; e2 < 8; ++e2) if (e2 != e0 && lg[e2] > v1m) { v1m = lg[e2]; e1 = e2; }
    float w0 = 1.f / (1.f + __expf((v1m - v0m) * 0.4f));
    float w1 = 1.f - w0;
    if (lane == 0) {
      int idx = (wv*16 + it) * 2;
      int s0 = atomicAdd(&lcnt[e0], 1);
      int s1 = atomicAdd(&lcnt[e1], 1);
      ltk[idx] = t;   lex[idx] = (unsigned char)e0; lwt[idx] = w0; lslot[idx] = s0;
      ltk[idx+1] = t; lex[idx+1] = (unsigned char)e1; lwt[idx+1] = w1; lslot[idx+1] = s1;
    }
  }
  __syncthreads();
  if (tid < 8) lbase[tid] = atomicAdd(&cnt[tid*16], lcnt[tid]);
  __syncthreads();
  if (tid < 128) {
    int e = lex[tid];
    int p = lbase[e] + lslot[tid];
    tokl[e*N_TOK + p] = ltk[tid];
    pwl[e*N_TOK + p]  = lwt[tid];
  }
}

// ---------------- fused expert FFN: 128 tokens/block, 8 waves, 32x32x16 MFMA
// G1: wave grid 4(row)x2(col): 32 tok x 64 f.  A(x) per-lane global, B(W1^T) LDS.
// G2: wave grid 2(row)x4(col): 64 tok x 128 d. A(h) LDS (+16B pad rows), B(W2^T) LDS.
// w1s [128f][64k] slot^(f&7), 3-buf dist-2; w2s [512d][32k] slot^(d&3), 2-buf dist-1.
__global__ __launch_bounds__(512, 2) void k_ffn(
    const unsigned short* __restrict__ xb,
    const unsigned short* __restrict__ w1t,   // (E, F, D) bf16
    const unsigned short* __restrict__ w2t,   // (E, D, F) bf16
    const float* __restrict__ b1, const float* __restrict__ b2,
    const int* __restrict__ tokl, const float* __restrict__ pwl,
    const int* __restrict__ cnt, float* __restrict__ out)
{
  const int e = blockIdx.x & 7;
  const int tile = blockIdx.x >> 3;
  const int count = cnt[e*16];
  const int row0 = tile * 128;
  if (row0 >= count) return;

  __shared__ unsigned short w1s[3][8192];   // 48 KB
  __shared__ unsigned short w2s[2][16384];  // 64 KB
  __shared__ unsigned short hsm[128*136];   // 34 KB (272B rows: 256B data + 16B pad)
  __shared__ float b1s[FF];                 // 8 KB
  __shared__ float b2s[DIM];                // 2 KB

  const int tid = threadIdx.x, lane = tid & 63, wv = tid >> 6;
  const int l31 = lane & 31, hi = lane >> 5;
  const int rg1 = wv >> 1, cg1 = wv & 1;
  const int rg2 = wv >> 2, cg2 = wv & 3;

  const unsigned short* w1e = w1t + (size_t)e*FF*DIM;
  const unsigned short* w2e = w2t + (size_t)e*DIM*FF;

  const int arow = row0 + rg1*32 + l31;
  const int atok = (arow < count) ? tokl[e*N_TOK + arow] : tokl[e*N_TOK];
  const unsigned short* xr = xb + (size_t)atok * DIM;

  // LDS read bases (shorts)
  const int w1rb0 = (cg1*64 + l31)*64;
  const int w1sl  = (hi ^ (lane & 7)) << 3;       // ^ (s<<4) per K16 substep
  const int w2rb0 = (cg2*128 + l31)*32;
  const int w2sl  = (hi ^ (lane & 3)) << 3;       // ^ (s2<<4)
  const int hA0   = (rg2*64 + l31)*136;           // + m*32*136

  auto stage_w1 = [&](int buf, int fi_, int kk_) {
#pragma unroll
    for (int j = 0; j < 2; ++j) {
      int f = wv*16 + j*8 + (lane >> 3);
      const unsigned short* src = w1e + (size_t)(fi_*128 + f)*DIM + kk_*64
                                + (((lane & 7) ^ ((lane >> 3) & 7)) << 3);
      gload_lds16(src, &w1s[buf][(wv*16 + j*8)*64]);
    }
  };
  auto stage_w2 = [&](int buf, int fi_, int c_) {
#pragma unroll
    for (int j = 0; j < 4; ++j) {
      int d = j*128 + wv*16 + (lane >> 2);
      const unsigned short* src = w2e + (size_t)d*FF + fi_*128 + c_*32
                                + (((lane & 3) ^ ((lane >> 2) & 3)) << 3);
      gload_lds16(src, &w2s[buf][j*4096 + wv*512]);
    }
  };

  // ---- prologue: biases (uniform 2 ops/thread), then prime pipeline ----
  gload_lds16(b1 + (size_t)e*FF + wv*256 + lane*4, &b1s[wv*256]);
  gload_lds16(b2 + (size_t)e*DIM + (wv & 1)*256 + lane*4, &b2s[(wv & 1)*256]);
  SBAR;

  const f32x16 fz = {0,0,0,0,0,0,0,0,0,0,0,0,0,0,0,0};
  f32x16 acc[2][4];
#pragma unroll
  for (int m = 0; m < 2; ++m)
#pragma unroll
    for (int n = 0; n < 4; ++n) acc[m][n] = fz;

  short8 xa[2][4];
#define XL(P, KOFF) do { \
  _Pragma("unroll") for (int s_ = 0; s_ < 4; ++s_) \
    xa[P][s_] = *(const short8*)(xr + (KOFF) + s_*16 + hi*8); } while (0)

  XL(0, 0); SBAR;
  stage_w1(0, 0, 0); SBAR;
  stage_w1(1, 0, 1); SBAR;

  for (int fi = 0; fi < 16; ++fi) {
    const int last = (fi == 15);
    f32x16 hacc[2] = {fz, fz};

    // ---------- GEMM1: 8 phases (K64 each) ----------
#pragma unroll
    for (int kk = 0; kk < 8; ++kk) {
      if (kk < 7) { XL((kk + 1) & 1, (kk + 1)*64); SBAR; }
      if (kk < 7) { BARN(6); } else { BARN(0); }
      if (kk < 6)       { stage_w1((kk + 2) % 3, fi, kk + 2); SBAR; }
      else if (kk == 7) { stage_w2(0, fi, 0); SBAR; }
      __builtin_amdgcn_s_setprio(1);
#pragma unroll
      for (int s_ = 0; s_ < 4; ++s_) {
#pragma unroll
        for (int n_ = 0; n_ < 2; ++n_) {
          short8 b_ = *(const short8*)&w1s[kk % 3][w1rb0 + n_*2048 + (w1sl ^ (s_ << 4))];
          hacc[n_] = __builtin_amdgcn_mfma_f32_32x32x16_bf16(xa[kk & 1][s_], b_, hacc[n_], 0, 0, 0);
        }
      }
      __builtin_amdgcn_s_setprio(0);
    }

    // ---------- bias + gelu -> h (padded rows, conflict-free) ----------
#pragma unroll
    for (int n = 0; n < 2; ++n) {
      int f = cg1*64 + n*32 + l31;
      float bias = b1s[fi*128 + f];
#pragma unroll
      for (int r = 0; r < 16; ++r) {
        int row = rg1*32 + (r & 3) + 8*(r >> 2) + 4*hi;
        float v = hacc[n][r] + bias;
        float u = 0.7978845608028654f * (v + 0.044715f*v*v*v);
        float g = v / (1.f + __expf(-2.f*u));      // tanh-approx gelu
        hsm[row*136 + f] = f2bf(g);
      }
    }

    // ---------- GEMM2: 4 phases (2 x K16 each) ----------
#pragma unroll
    for (int c = 0; c < 4; ++c) {
      if (c == 3 && !last) { XL(0, 0); SBAR; }
      if (c == 0)      { BARNL(0); }
      else if (c < 3)  { BARN(0); }
      else if (!last)  { BARN(4); }
      else             { BARN(0); }
      if (c < 3)       { stage_w2((c + 1) & 1, fi, c + 1); SBAR; }
      else if (!last)  { stage_w1(0, fi + 1, 0); stage_w1(1, fi + 1, 1); SBAR; }
      __builtin_amdgcn_s_setprio(1);
#pragma unroll
      for (int s2_ = 0; s2_ < 2; ++s2_) {
        short8 a0_ = *(const short8*)&hsm[hA0 + c*32 + s2_*16 + hi*8];
        short8 a1_ = *(const short8*)&hsm[hA0 + 4352 + c*32 + s2_*16 + hi*8];
#pragma unroll
        for (int n_ = 0; n_ < 4; ++n_) {
          short8 b_ = *(const short8*)&w2s[c & 1][w2rb0 + n_*1024 + (w2sl ^ (s2_ << 4))];
          acc[0][n_] = __builtin_amdgcn_mfma_f32_32x32x16_bf16(a0_, b_, acc[0][n_], 0, 0, 0);
          acc[1][n_] = __builtin_amdgcn_mfma_f32_32x32x16_bf16(a1_, b_, acc[1][n_], 0, 0, 0);
        }
      }
      __builtin_amdgcn_s_setprio(0);
    }
  }
#undef XL

  // ---------- epilogue: weighted atomic scatter-add ----------
#pragma unroll
  for (int m = 0; m < 2; ++m) {
#pragma unroll
    for (int r = 0; r < 16; ++r) {
      int ridx = row0 + rg2*64 + m*32 + (r & 3) + 8*(r >> 2) + 4*hi;
      if (ridx < count) {
        int tk = tokl[e*N_TOK + ridx];
        float wg = pwl[e*N_TOK + ridx];
#pragma unroll
        for (int n = 0; n < 4; ++n) {
          int d = cg2*128 + n*32 + l31;
          atomicAdd(out + (size_t)tk*DIM + d, (acc[m][n][r] + b2s[d]) * wg);
        }
      }
    }
  }
}

extern "C" void kernel_launch(void* const* d_in, const int* in_sizes, int n_in,
                              void* d_out, int out_size, void* d_ws, size_t ws_size,
                              hipStream_t stream)
{
  const float* x  = (const float*)d_in[0];
  const float* Wr = (const float*)d_in[1];
  const float* W1 = (const float*)d_in[2];
  const float* b1 = (const float*)d_in[3];
  const float* W2 = (const float*)d_in[4];
  const float* b2 = (const float*)d_in[5];
  float* out = (float*)d_out;
  (void)in_sizes; (void)n_in; (void)ws_size;

  char* ws = (char*)d_ws;
  unsigned short* xb  = (unsigned short*)(ws);                // 64 MB
  unsigned short* w1t = (unsigned short*)(ws + 67108864);     // 16 MB
  unsigned short* w2t = (unsigned short*)(ws + 83886080);     // 16 MB
  int*   tokl = (int*)(ws + 100663296);                       // 2 MB
  float* pwl  = (float*)(ws + 102760448);                     // 2 MB
  int*   cnt  = (int*)(ws + 104857600);                       // 512 B

  hipMemsetAsync(cnt, 0, NE*16*sizeof(int), stream);
  hipMemsetAsync(d_out, 0, (size_t)out_size*sizeof(float), stream);

  dim3 g1(FF/32, DIM/32, NE);
  k_transpose_cast<<<g1, 256, 0, stream>>>(W1, w1t, DIM, FF);
  dim3 g2(DIM/32, FF/32, NE);
  k_transpose_cast<<<g2, 256, 0, stream>>>(W2, w2t, FF, DIM);

  k_router<<<N_TOK/64, 256, 0, stream>>>(x, Wr, xb, tokl, pwl, cnt);

  k_ffn<<<NE * (N_TOK/128), 512, 0, stream>>>(xb, w1t, w2t, b1, b2, tokl, pwl, cnt, out);
}